// Round 14
// baseline (949.254 us; speedup 1.0000x reference)
//
#include <hip/hip_runtime.h>
#include <cmath>

// ---- model constants ----
constexpr int kB = 4, kN = 640, kD = 1024, kH = 16, kDH = 64;
constexpr int kDepth = 6, kMLP = 2048, kPD = 3072, kNC = 1000, kM = 18;
constexpr float kScale = 0.125f;        // DH^-0.5
constexpr float kNegInf = -3.4028235e38f;

typedef __bf16 bf16;
typedef __attribute__((ext_vector_type(8))) __bf16 bf16x8;
typedef __attribute__((ext_vector_type(4))) __bf16 bf16x4;
typedef __attribute__((ext_vector_type(4))) float f32x4;

#define AS1 __attribute__((address_space(1)))
#define AS3 __attribute__((address_space(3)))

__device__ __forceinline__ void gload16(const void* g, void* l) {
  __builtin_amdgcn_global_load_lds((AS1 void*)g, (AS3 void*)l, 16, 0, 0);
}

// ---- wtbuf element offsets (bf16 elems) ----
constexpr size_t kMEG = 1048576;
constexpr size_t kOffPe = 0;                              // 3072x1024
constexpr size_t kLayer0 = 3 * kMEG;
constexpr size_t kLayerSz = 8 * kMEG;                     // WqT 1M | WkvT 2M | WoT 1M | W1T 2M | W2T 2M
constexpr size_t kOffPool = kLayer0 + 6 * kLayerSz;
constexpr size_t kOffPlWq = kOffPool;
constexpr size_t kOffPlWkv = kOffPool + 1 * kMEG;
constexpr size_t kOffPlWo = kOffPool + 3 * kMEG;
constexpr size_t kOffHead = kOffPool + 4 * kMEG;

// ============================================================
// Batched weight transpose (round-11 variant — best measured).
// 64x64 tiles: float4 reads, LDS [64][65], bf16x8 coalesced writes.
// grid = (768, 35).
// ============================================================
__global__ __launch_bounds__(256) void wt_all_kernel(
    const float* __restrict__ pe, const float* __restrict__ wq,
    const float* __restrict__ wkv, const float* __restrict__ wo,
    const float* __restrict__ w1, const float* __restrict__ w2,
    const float* __restrict__ plq, const float* __restrict__ plkv,
    const float* __restrict__ plo, const float* __restrict__ whead,
    bf16* __restrict__ WTB) {
  const int j = blockIdx.y;
  const float* W;
  size_t doff;
  int K, Nc, Np;
  if (j == 0) {
    W = pe; K = 3072; Nc = 1024; Np = 1024; doff = kOffPe;
  } else if (j < 31) {
    const int l = (j - 1) / 5, w = (j - 1) % 5;
    const size_t lbase = kLayer0 + (size_t)l * kLayerSz;
    switch (w) {
      case 0:  W = wq  + (size_t)l * kMEG;     K = 1024; Nc = 1024; doff = lbase;            break;
      case 1:  W = wkv + (size_t)l * 2 * kMEG; K = 1024; Nc = 2048; doff = lbase + kMEG;     break;
      case 2:  W = wo  + (size_t)l * kMEG;     K = 1024; Nc = 1024; doff = lbase + 3 * kMEG; break;
      case 3:  W = w1  + (size_t)l * 2 * kMEG; K = 1024; Nc = 2048; doff = lbase + 4 * kMEG; break;
      default: W = w2  + (size_t)l * 2 * kMEG; K = 2048; Nc = 1024; doff = lbase + 6 * kMEG; break;
    }
    Np = Nc;
  } else if (j == 31) { W = plq;  K = 1024; Nc = 1024; Np = 1024; doff = kOffPlWq; }
  else if (j == 32)   { W = plkv; K = 1024; Nc = 2048; Np = 2048; doff = kOffPlWkv; }
  else if (j == 33)   { W = plo;  K = 1024; Nc = 1024; Np = 1024; doff = kOffPlWo; }
  else                { W = whead; K = 1024; Nc = 1000; Np = 1024; doff = kOffHead; }
  const int nbx = Np >> 6;
  const int ntiles = nbx * (K >> 6);
  const int tile = blockIdx.x;
  if (tile >= ntiles) return;
  const int n0 = (tile % nbx) * 64, k0 = (tile / nbx) * 64;
  bf16* WT = WTB + doff;
  __shared__ float s[64][65];
  const int tid = threadIdx.x;
  if (n0 + 64 <= Nc) {
#pragma unroll
    for (int i = 0; i < 4; ++i) {
      const int c = i * 256 + tid;
      const int r = c >> 4, cq = c & 15;
      const float4 v = *(const float4*)(W + (size_t)(k0 + r) * Nc + n0 + cq * 4);
      s[r][cq * 4 + 0] = v.x; s[r][cq * 4 + 1] = v.y;
      s[r][cq * 4 + 2] = v.z; s[r][cq * 4 + 3] = v.w;
    }
  } else {
#pragma unroll
    for (int i = 0; i < 4; ++i) {
      const int c = i * 256 + tid;
      const int r = c >> 4, cq = c & 15;
#pragma unroll
      for (int e = 0; e < 4; ++e) {
        const int n = n0 + cq * 4 + e;
        s[r][cq * 4 + e] = (n < Nc) ? W[(size_t)(k0 + r) * Nc + n] : 0.f;
      }
    }
  }
  __syncthreads();
#pragma unroll
  for (int i = 0; i < 2; ++i) {
    const int c = i * 256 + tid;
    const int n = c >> 3, kq = c & 7;
    bf16x8 w;
#pragma unroll
    for (int e = 0; e < 8; ++e) w[e] = (bf16)s[kq * 8 + e][n];
    *(bf16x8*)(WT + (size_t)(n0 + n) * K + k0 + kq * 8) = w;
  }
}

// ============================================================
// Image-span precompute.
// ============================================================
__global__ __launch_bounds__(64) void span_kernel(
    const int* __restrict__ ids, int2* __restrict__ spans) {
  const int img = blockIdx.x, b = blockIdx.y;
  const int want = (img < kM) ? img : -1;
  int lo = kN, hi = -1;
  for (int j = threadIdx.x; j < kN; j += 64) {
    if (ids[b * kN + j] == want) { lo = min(lo, j); hi = max(hi, j); }
  }
#pragma unroll
  for (int off = 32; off; off >>= 1) {
    lo = min(lo, __shfl_xor(lo, off));
    hi = max(hi, __shfl_xor(hi, off));
  }
  if (threadIdx.x == 0) spans[b * (kM + 1) + img] = make_int2(lo, hi);
}

// ============================================================
// LayerNorm, f32 input. float4 loads.
// ============================================================
template <typename OT>
__global__ __launch_bounds__(256) void ln_kernel(
    const float* __restrict__ in, OT* __restrict__ out,
    const float* __restrict__ g, const float* __restrict__ b, int K) {
  const int row = blockIdx.x;
  const float* x = in + (size_t)row * K;
  OT* o = out + (size_t)row * K;
  const int K4 = K >> 2;
  float s = 0.f, s2 = 0.f;
  for (int c = threadIdx.x; c < K4; c += 256) {
    const float4 v = ((const float4*)x)[c];
    s += v.x + v.y + v.z + v.w;
    s2 += v.x * v.x + v.y * v.y + v.z * v.z + v.w * v.w;
  }
#pragma unroll
  for (int off = 32; off; off >>= 1) { s += __shfl_down(s, off); s2 += __shfl_down(s2, off); }
  __shared__ float ls[4], ls2[4];
  __shared__ float sm, sr;
  const int wid = threadIdx.x >> 6, lane = threadIdx.x & 63;
  if (lane == 0) { ls[wid] = s; ls2[wid] = s2; }
  __syncthreads();
  if (threadIdx.x == 0) {
    float a = ls[0] + ls[1] + ls[2] + ls[3];
    float a2 = ls2[0] + ls2[1] + ls2[2] + ls2[3];
    float mean = a / K;
    float var = a2 / K - mean * mean;
    sm = mean; sr = rsqrtf(var + 1e-5f);
  }
  __syncthreads();
  const float mean = sm, r = sr;
  for (int c = threadIdx.x; c < K4; c += 256) {
    const float4 v = ((const float4*)x)[c];
    const float4 gv = ((const float4*)g)[c];
    const float4 bv = ((const float4*)b)[c];
    const int d = c * 4;
    o[d + 0] = (OT)((v.x - mean) * r * gv.x + bv.x);
    o[d + 1] = (OT)((v.y - mean) * r * gv.y + bv.y);
    o[d + 2] = (OT)((v.z - mean) * r * gv.z + bv.z);
    o[d + 3] = (OT)((v.w - mean) * r * gv.w + bv.w);
  }
}

// ============================================================
// LayerNorm, bf16 in -> bf16 out, K=1024 fixed.
// ============================================================
__global__ __launch_bounds__(256) void ln_bf_kernel(
    const bf16* __restrict__ in, bf16* __restrict__ out,
    const float* __restrict__ g, const float* __restrict__ b) {
  const int row = blockIdx.x;
  const bf16* x = in + (size_t)row * kD;
  bf16* o = out + (size_t)row * kD;
  const int c = threadIdx.x;
  const bf16x4 v4 = ((const bf16x4*)x)[c];
  float f[4];
  float s = 0.f, s2 = 0.f;
#pragma unroll
  for (int e = 0; e < 4; ++e) {
    f[e] = (float)v4[e];
    s += f[e]; s2 += f[e] * f[e];
  }
#pragma unroll
  for (int off = 32; off; off >>= 1) { s += __shfl_down(s, off); s2 += __shfl_down(s2, off); }
  __shared__ float ls[4], ls2[4];
  __shared__ float sm, sr;
  const int wid = c >> 6, lane = c & 63;
  if (lane == 0) { ls[wid] = s; ls2[wid] = s2; }
  __syncthreads();
  if (c == 0) {
    float a = ls[0] + ls[1] + ls[2] + ls[3];
    float a2 = ls2[0] + ls2[1] + ls2[2] + ls2[3];
    float mean = a / kD;
    sm = mean; sr = rsqrtf(a2 / kD - mean * mean + 1e-5f);
  }
  __syncthreads();
  const float mean = sm, r = sr;
  const float4 gv = ((const float4*)g)[c];
  const float4 bv = ((const float4*)b)[c];
  bf16x4 ov;
  ov[0] = (bf16)((f[0] - mean) * r * gv.x + bv.x);
  ov[1] = (bf16)((f[1] - mean) * r * gv.y + bv.y);
  ov[2] = (bf16)((f[2] - mean) * r * gv.z + bv.z);
  ov[3] = (bf16)((f[3] - mean) * r * gv.w + bv.w);
  ((bf16x4*)o)[c] = ov;
}

// ============================================================
// Fused pe_ln2 + factorized pos-embed add. f32 in, bf16 out.
// ============================================================
__global__ __launch_bounds__(256) void ln_pos_kernel(
    const float* __restrict__ in, bf16* __restrict__ out,
    const float* __restrict__ g, const float* __restrict__ b,
    const float* __restrict__ ph, const float* __restrict__ pw,
    const int* __restrict__ hi, const int* __restrict__ wi) {
  const int row = blockIdx.x;
  const float* x = in + (size_t)row * kD;
  bf16* o = out + (size_t)row * kD;
  const int c = threadIdx.x;
  const float4 v = ((const float4*)x)[c];
  float s = v.x + v.y + v.z + v.w;
  float s2 = v.x * v.x + v.y * v.y + v.z * v.z + v.w * v.w;
#pragma unroll
  for (int off = 32; off; off >>= 1) { s += __shfl_down(s, off); s2 += __shfl_down(s2, off); }
  __shared__ float ls[4], ls2[4];
  __shared__ float sm, sr;
  const int wid = threadIdx.x >> 6, lane = threadIdx.x & 63;
  if (lane == 0) { ls[wid] = s; ls2[wid] = s2; }
  __syncthreads();
  if (threadIdx.x == 0) {
    float a = ls[0] + ls[1] + ls[2] + ls[3];
    float a2 = ls2[0] + ls2[1] + ls2[2] + ls2[3];
    float mean = a / kD;
    float var = a2 / kD - mean * mean;
    sm = mean; sr = rsqrtf(var + 1e-5f);
  }
  __syncthreads();
  const float mean = sm, r = sr;
  const float4* phr = (const float4*)(ph + (size_t)hi[row] * kD);
  const float4* pwr = (const float4*)(pw + (size_t)wi[row] * kD);
  const float4 gv = ((const float4*)g)[c];
  const float4 bv = ((const float4*)b)[c];
  const float4 hv = phr[c], wv = pwr[c];
  bf16x4 ov;
  ov[0] = (bf16)((v.x - mean) * r * gv.x + bv.x + hv.x + wv.x);
  ov[1] = (bf16)((v.y - mean) * r * gv.y + bv.y + hv.y + wv.y);
  ov[2] = (bf16)((v.z - mean) * r * gv.z + bv.z + hv.z + wv.z);
  ov[3] = (bf16)((v.w - mean) * r * gv.w + bv.w + hv.w + wv.w);
  ((bf16x4*)o)[c] = ov;
}

// ============================================================
// Fused pool-query chain: LN(pool_q) -> @pl_Wq^T(bf16) -> head LN.
// ============================================================
__global__ __launch_bounds__(256) void poolq_kernel(
    const float* __restrict__ pq, const float* __restrict__ lg,
    const float* __restrict__ lb, const bf16* __restrict__ WqT,
    const float* __restrict__ qg, const float* __restrict__ qb,
    float* __restrict__ qpool) {
  const int h = blockIdx.x, tid = threadIdx.x;
  __shared__ float qs[1024];
  __shared__ float red[256];
  __shared__ float ls[4], ls2[4];
  __shared__ float sm, sr;
  const float4 v = ((const float4*)pq)[tid];
  float s = v.x + v.y + v.z + v.w;
  float s2 = v.x * v.x + v.y * v.y + v.z * v.z + v.w * v.w;
#pragma unroll
  for (int off = 32; off; off >>= 1) { s += __shfl_down(s, off); s2 += __shfl_down(s2, off); }
  const int wid = tid >> 6, lane = tid & 63;
  if (lane == 0) { ls[wid] = s; ls2[wid] = s2; }
  __syncthreads();
  if (tid == 0) {
    float a = ls[0] + ls[1] + ls[2] + ls[3];
    float a2 = ls2[0] + ls2[1] + ls2[2] + ls2[3];
    float mean = a / kD;
    sm = mean; sr = rsqrtf(a2 / kD - mean * mean + 1e-5f);
  }
  __syncthreads();
  {
    const float mean = sm, r = sr;
    const float4 gv = ((const float4*)lg)[tid];
    const float4 bv = ((const float4*)lb)[tid];
    qs[tid * 4 + 0] = (v.x - mean) * r * gv.x + bv.x;
    qs[tid * 4 + 1] = (v.y - mean) * r * gv.y + bv.y;
    qs[tid * 4 + 2] = (v.z - mean) * r * gv.z + bv.z;
    qs[tid * 4 + 3] = (v.w - mean) * r * gv.w + bv.w;
  }
  __syncthreads();
  const int d = tid & 63, qq = tid >> 6;
  const bf16* wrow = WqT + (size_t)(h * 64 + d) * 1024 + qq * 256;
  const float* qp = qs + qq * 256;
  float part = 0.f;
  for (int k = 0; k < 256; k += 8) {
    const bf16x8 w8 = *(const bf16x8*)(wrow + k);
#pragma unroll
    for (int e = 0; e < 8; ++e) part += qp[k + e] * (float)w8[e];
  }
  red[tid] = part;
  __syncthreads();
  if (tid < 64) {
    const float dot = red[tid] + red[tid + 64] + red[tid + 128] + red[tid + 192];
    float hs = dot, hs2 = dot * dot;
#pragma unroll
    for (int off = 32; off; off >>= 1) { hs += __shfl_xor(hs, off); hs2 += __shfl_xor(hs2, off); }
    const float m = hs * (1.f / kDH);
    const float r = rsqrtf(hs2 * (1.f / kDH) - m * m + 1e-5f);
    qpool[h * 64 + tid] = (dot - m) * r * qg[tid] + qb[tid];
  }
}

// ============================================================
// 64x(NI*32) MFMA GEMM, BK=64, 2-buffer LDS + global_load_lds
// prefetch. T2 XOR-swizzle, XCD-chunked blockIdx swizzle.
// res bf16. HLN for pool kv (NI=4).
// ============================================================
template <int NI, bool OUT_BF, bool GELU, bool HLN>
__global__ __launch_bounds__(256) void gemm64_kernel(
    const bf16* __restrict__ A, const bf16* __restrict__ WT,
    float* __restrict__ Cf, bf16* __restrict__ Cb,
    const float* __restrict__ bias, const bf16* __restrict__ res,
    const float* __restrict__ hg, const float* __restrict__ hb,
    int K, int Ncol, int nbx) {
  constexpr int BN = NI * 32;
  __shared__ __align__(16) bf16 As[2][64 * 64];
  __shared__ __align__(16) bf16 Bs[2][BN * 64];
  const int tid = threadIdx.x, lane = tid & 63, wid = tid >> 6;
  const int wr = wid >> 1, wc = wid & 1;
  const int cpx = gridDim.x >> 3;
  const int swz = (blockIdx.x & 7) * cpx + (blockIdx.x >> 3);
  const int row0 = (swz / nbx) * 64, col0 = (swz % nbx) * BN;
  const int fr = lane & 15, fg = lane >> 4;
  f32x4 acc[2][NI] = {};
  bf16* sA = As[0]; bf16* sB = Bs[0];
  bf16* dA = As[1]; bf16* dB = Bs[1];

  auto stage = [&](bf16* tA, bf16* tB, int kt) {
#pragma unroll
    for (int i = 0; i < 2; ++i) {
      const int c = i * 256 + tid;
      const int r = c >> 3, ci = c & 7;
      gload16(A + (size_t)(row0 + r) * K + kt + ((ci ^ (r & 7)) * 8),
              tA + (i * 256 + wid * 64) * 8);
    }
#pragma unroll
    for (int i = 0; i < NI; ++i) {
      const int c = i * 256 + tid;
      const int r = c >> 3, ci = c & 7;
      gload16(WT + (size_t)(col0 + r) * K + kt + ((ci ^ (r & 7)) * 8),
              tB + (i * 256 + wid * 64) * 8);
    }
  };
  auto compute = [&](const bf16* tA, const bf16* tB) {
#pragma unroll
    for (int kk = 0; kk < 2; ++kk) {
      bf16x8 af[2], bfr[NI];
#pragma unroll
      for (int mi = 0; mi < 2; ++mi) {
        const int r = wr * 32 + mi * 16 + fr;
        af[mi] = *(const bf16x8*)(tA + r * 64 + (((kk * 4 + fg) ^ (r & 7)) * 8));
      }
#pragma unroll
      for (int ni = 0; ni < NI; ++ni) {
        const int r = wc * (NI * 16) + ni * 16 + fr;
        bfr[ni] = *(const bf16x8*)(tB + r * 64 + (((kk * 4 + fg) ^ (r & 7)) * 8));
      }
#pragma unroll
      for (int mi = 0; mi < 2; ++mi)
#pragma unroll
        for (int ni = 0; ni < NI; ++ni)
          acc[mi][ni] = __builtin_amdgcn_mfma_f32_16x16x32_bf16(af[mi], bfr[ni], acc[mi][ni], 0, 0, 0);
    }
  };

  const int NT = K >> 6;
  stage(sA, sB, 0);
  __syncthreads();
  for (int t = 1; t < NT; ++t) {
    stage(dA, dB, t * 64);
    compute(sA, sB);
    __syncthreads();
    bf16* u;
    u = sA; sA = dA; dA = u;
    u = sB; sB = dB; dB = u;
  }
  compute(sA, sB);

  const int rb = row0 + wr * 32 + fg * 4;
  const int cb = col0 + wc * (NI * 16) + fr;
  float hm[2][4], hr[2][4];
  if (HLN) {
#pragma unroll
    for (int mi = 0; mi < 2; ++mi)
#pragma unroll
      for (int r = 0; r < 4; ++r) {
        float s = 0.f, s2 = 0.f;
#pragma unroll
        for (int ni = 0; ni < NI; ++ni) {
          const float v = acc[mi][ni][r];
          s += v; s2 += v * v;
        }
#pragma unroll
        for (int off = 1; off < 16; off <<= 1) {
          s += __shfl_xor(s, off); s2 += __shfl_xor(s2, off);
        }
        const float m = s * (1.f / kDH);
        hm[mi][r] = m;
        hr[mi][r] = rsqrtf(s2 * (1.f / kDH) - m * m + 1e-5f);
      }
  }
  const bool kHalf = HLN && (cb < kD);
#pragma unroll
  for (int mi = 0; mi < 2; ++mi) {
#pragma unroll
    for (int ni = 0; ni < NI; ++ni) {
      const int cc = cb + ni * 16;
      const float bb = bias ? bias[cc] : 0.f;
      const float hgv = HLN ? hg[ni * 16 + fr] : 0.f;
      const float hbv = HLN ? hb[ni * 16 + fr] : 0.f;
#pragma unroll
      for (int r = 0; r < 4; ++r) {
        const int rr = rb + mi * 16 + r;
        float v = acc[mi][ni][r] + bb;
        if (res) v += (float)res[(size_t)rr * Ncol + cc];
        if (GELU) v = 0.5f * v * (1.f + erff(v * 0.70710678118654752f));
        if (HLN && kHalf) v = (v - hm[mi][r]) * hr[mi][r] * hgv + hbv;
        if (OUT_BF) Cb[(size_t)rr * Ncol + cc] = (bf16)v;
        else        Cf[(size_t)rr * Ncol + cc] = v;
      }
    }
  }
}

// ============================================================
// Guarded tail GEMM (reg-staged 64x128): small M.
// ============================================================
template <bool OUT_BF>
__global__ __launch_bounds__(256) void gemm_tail_kernel(
    const bf16* __restrict__ A, const bf16* __restrict__ WT,
    float* __restrict__ Cf, bf16* __restrict__ Cb,
    const float* __restrict__ bias, const float* __restrict__ resv,
    int Mr, int K, int Nc, int ldc, int resmode) {
  __shared__ __align__(16) bf16 As[64][40];
  __shared__ __align__(16) bf16 Bs[128][40];
  const int tid = threadIdx.x;
  const int lane = tid & 63, wid = tid >> 6;
  const int row0 = blockIdx.y * 64, col0 = blockIdx.x * 128;
  f32x4 acc[4][2] = {};
  const int am = tid >> 2, ako = (tid & 3) * 8;
  const int fr = lane & 15, fg = (lane >> 4) * 8;
  for (int k0 = 0; k0 < K; k0 += 32) {
    if (row0 + am < Mr)
      *(bf16x8*)&As[am][ako] = *(const bf16x8*)(A + (size_t)(row0 + am) * K + k0 + ako);
    else {
      bf16x8 z = {};
      *(bf16x8*)&As[am][ako] = z;
    }
#pragma unroll
    for (int it = 0; it < 2; ++it) {
      const int c = it * 256 + tid;
      const int n = c >> 2, ko = (c & 3) * 8;
      *(bf16x8*)&Bs[n][ko] = *(const bf16x8*)(WT + (size_t)(col0 + n) * K + k0 + ko);
    }
    __syncthreads();
    bf16x8 af[4], bfr[2];
#pragma unroll
    for (int mi = 0; mi < 4; ++mi) af[mi] = *(const bf16x8*)&As[mi * 16 + fr][fg];
#pragma unroll
    for (int ni = 0; ni < 2; ++ni) bfr[ni] = *(const bf16x8*)&Bs[wid * 32 + ni * 16 + fr][fg];
#pragma unroll
    for (int mi = 0; mi < 4; ++mi)
#pragma unroll
      for (int ni = 0; ni < 2; ++ni)
        acc[mi][ni] = __builtin_amdgcn_mfma_f32_16x16x32_bf16(af[mi], bfr[ni], acc[mi][ni], 0, 0, 0);
    __syncthreads();
  }
  const int r4 = (lane >> 4) * 4;
  const int cc0 = col0 + wid * 32 + (lane & 15);
#pragma unroll
  for (int mi = 0; mi < 4; ++mi) {
#pragma unroll
    for (int ni = 0; ni < 2; ++ni) {
      const int cc = cc0 + ni * 16;
      if (cc >= Nc) continue;
#pragma unroll
      for (int r = 0; r < 4; ++r) {
        const int rr = row0 + mi * 16 + r4 + r;
        if (rr >= Mr) continue;
        float v = acc[mi][ni][r];
        if (bias) v += bias[cc];
        if (resmode == 1) v += resv[(size_t)rr * ldc + cc];
        else if (resmode == 2) v += resv[cc];
        if (OUT_BF) Cb[(size_t)rr * ldc + cc] = (bf16)v;
        else        Cf[(size_t)rr * ldc + cc] = v;
      }
    }
  }
}

// ============================================================
// Block-diagonal MFMA attention, bf16 qkv input [B,N,3072].
// T-aware MFMA pruning: QK^T only for ni < ceil(T/16) (skipped
// sacc stay 0 and are masked to -inf -> P=0, bit-identical);
// PV skips the k0=32 half when T<=32 (P cols & V rows there = 0).
// ============================================================
__global__ __launch_bounds__(256) void attn_kernel(
    const bf16* __restrict__ qkv, const int2* __restrict__ spans,
    const float* __restrict__ qg, const float* __restrict__ qb,
    const float* __restrict__ kg, const float* __restrict__ kb,
    bf16* __restrict__ o) {
  const int h = blockIdx.x, img = blockIdx.y, b = blockIdx.z;
  const int tid = threadIdx.x, lane = tid & 63, wid = tid >> 6;
  __shared__ __align__(16) bf16 Qs[64][72];
  __shared__ __align__(16) bf16 Ks[64][72];
  __shared__ __align__(16) bf16 Vt[64][72];
  __shared__ __align__(16) bf16 Ps[64][72];
  const int2 sp = spans[b * (kM + 1) + img];
  if (sp.y < 0) return;
  const int start = sp.x, T = sp.y - sp.x + 1;
  if (img == kM) {
    for (int j = start + wid; j <= sp.y; j += 4)
      o[((size_t)(b * kN + j)) * kD + h * kDH + lane] = (bf16)0.f;
    return;
  }
  const int nT = (T + 15) >> 4;          // # of active 16-col score blocks
#pragma unroll
  for (int it = 0; it < 2; ++it) {
    const int ch = it * 256 + tid;
    const int r = ch >> 3, d0 = (ch & 7) * 8;
    if (r < T) {
      const bf16* base = qkv + ((size_t)(b * kN + start + r)) * 3072 + h * kDH + d0;
      const bf16x8 qv = *(const bf16x8*)(base);
      const bf16x8 kv = *(const bf16x8*)(base + 1024);
      const bf16x8 vv = *(const bf16x8*)(base + 2048);
      float qf[8], kf[8];
      float sq = 0.f, sq2 = 0.f, sk = 0.f, sk2 = 0.f;
#pragma unroll
      for (int e = 0; e < 8; ++e) {
        qf[e] = (float)qv[e]; kf[e] = (float)kv[e];
        sq += qf[e]; sq2 += qf[e] * qf[e];
        sk += kf[e]; sk2 += kf[e] * kf[e];
      }
#pragma unroll
      for (int off = 1; off < 8; off <<= 1) {
        sq += __shfl_xor(sq, off); sq2 += __shfl_xor(sq2, off);
        sk += __shfl_xor(sk, off); sk2 += __shfl_xor(sk2, off);
      }
      const float qm = sq * (1.f / 64);
      const float qr = rsqrtf(sq2 * (1.f / 64) - qm * qm + 1e-5f);
      const float km = sk * (1.f / 64);
      const float kr = rsqrtf(sk2 * (1.f / 64) - km * km + 1e-5f);
      bf16x8 qw, kw;
#pragma unroll
      for (int e = 0; e < 8; ++e) {
        qw[e] = (bf16)((qf[e] - qm) * qr * qg[d0 + e] + qb[d0 + e]);
        kw[e] = (bf16)((kf[e] - km) * kr * kg[d0 + e] + kb[d0 + e]);
      }
      *(bf16x8*)&Qs[r][d0] = qw;
      *(bf16x8*)&Ks[r][d0] = kw;
#pragma unroll
      for (int e = 0; e < 8; ++e) Vt[d0 + e][r] = vv[e];
    } else {
      const bf16x8 z = {};
      *(bf16x8*)&Qs[r][d0] = z;
      *(bf16x8*)&Ks[r][d0] = z;
#pragma unroll
      for (int e = 0; e < 8; ++e) Vt[d0 + e][r] = (bf16)0.f;
    }
  }
  __syncthreads();
  const int fr = lane & 15, fg = lane >> 4;
  const int r0 = wid * 16;
  f32x4 sacc[4] = {};
  __builtin_amdgcn_s_setprio(1);
#pragma unroll
  for (int k0 = 0; k0 < 64; k0 += 32) {
    const bf16x8 aq = *(const bf16x8*)&Qs[r0 + fr][k0 + fg * 8];
#pragma unroll
    for (int ni = 0; ni < 4; ++ni) {
      if (ni >= nT) continue;          // wave-uniform skip; sacc stays 0 -> masked
      const bf16x8 bk = *(const bf16x8*)&Ks[ni * 16 + fr][k0 + fg * 8];
      sacc[ni] = __builtin_amdgcn_mfma_f32_16x16x32_bf16(aq, bk, sacc[ni], 0, 0, 0);
    }
  }
  __builtin_amdgcn_s_setprio(0);
  float inv[4];
#pragma unroll
  for (int r = 0; r < 4; ++r) {
    float mx = kNegInf;
#pragma unroll
    for (int ni = 0; ni < 4; ++ni) {
      const float s = (ni * 16 + fr < T) ? sacc[ni][r] * kScale : kNegInf;
      sacc[ni][r] = s;
      mx = fmaxf(mx, s);
    }
#pragma unroll
    for (int off = 1; off < 16; off <<= 1) mx = fmaxf(mx, __shfl_xor(mx, off));
    float sum = 0.f;
#pragma unroll
    for (int ni = 0; ni < 4; ++ni) {
      const float p = __expf(sacc[ni][r] - mx);
      sacc[ni][r] = p;
      sum += p;
    }
#pragma unroll
    for (int off = 1; off < 16; off <<= 1) sum += __shfl_xor(sum, off);
    inv[r] = 1.f / sum;
  }
#pragma unroll
  for (int ni = 0; ni < 4; ++ni)
#pragma unroll
    for (int r = 0; r < 4; ++r)
      Ps[r0 + fg * 4 + r][ni * 16 + fr] = (bf16)sacc[ni][r];
  f32x4 oacc[4] = {};
  const int kHi = (T > 32) ? 64 : 32;   // P cols >=32 and V rows >=32 are 0 when T<=32
  __builtin_amdgcn_s_setprio(1);
  for (int k0 = 0; k0 < kHi; k0 += 32) {
    const bf16x8 ap = *(const bf16x8*)&Ps[r0 + fr][k0 + fg * 8];
#pragma unroll
    for (int ni = 0; ni < 4; ++ni) {
      const bf16x8 bv = *(const bf16x8*)&Vt[ni * 16 + fr][k0 + fg * 8];
      oacc[ni] = __builtin_amdgcn_mfma_f32_16x16x32_bf16(ap, bv, oacc[ni], 0, 0, 0);
    }
  }
  __builtin_amdgcn_s_setprio(0);
#pragma unroll
  for (int r = 0; r < 4; ++r) {
    const int i = r0 + fg * 4 + r;
    if (i < T) {
      const size_t orow = ((size_t)(b * kN + start + i)) * kD + h * kDH;
      const float iv = inv[r];
#pragma unroll
      for (int ni = 0; ni < 4; ++ni)
        o[orow + ni * 16 + fr] = (bf16)(oacc[ni][r] * iv);
    }
  }
}

// ============================================================
// Attention pooling: one wave per (b,m,h). kv bf16 [B,N,2048].
// ============================================================
__global__ __launch_bounds__(64) void poolattn_kernel(
    const float* __restrict__ qp, const bf16* __restrict__ kv,
    const int2* __restrict__ spans, bf16* __restrict__ o) {
  const int blk = blockIdx.x;
  const int h = blk % kH;
  const int bm = blk / kH;
  const int m = bm % kM, b = bm / kM;
  const int lane = threadIdx.x;
  __shared__ float sc[kN];
  __shared__ float qs[kDH];
  qs[lane] = qp[h * kDH + lane];
  __syncthreads();
  const int2 sp = spans[b * (kM + 1) + m];
  const int jlo = sp.x, jhi = sp.y + 1;
  float mymax = kNegInf;
  for (int j = jlo + lane; j < jhi; j += 64) {
    const bf16* krow = kv + ((size_t)(b * kN + j)) * (2 * kD) + h * kDH;
    float dot = 0.f;
#pragma unroll
    for (int d = 0; d < kDH; ++d) dot += qs[d] * (float)krow[d];
    const float s = dot * kScale;
    sc[j] = s;
    mymax = fmaxf(mymax, s);
  }
#pragma unroll
  for (int off = 32; off; off >>= 1) mymax = fmaxf(mymax, __shfl_xor(mymax, off));
  float mysum = 0.f;
  for (int j = jlo + lane; j < jhi; j += 64) {
    const float p = __expf(sc[j] - mymax);
    sc[j] = p;
    mysum += p;
  }
#pragma unroll
  for (int off = 32; off; off >>= 1) mysum += __shfl_xor(mysum, off);
  const float inv = 1.f / mysum;
  __syncthreads();
  float acc = 0.f;
  const bf16* vptr = kv + ((size_t)(b * kN + jlo)) * (2 * kD) + kD + h * kDH + lane;
  for (int j = jlo; j < jhi; ++j, vptr += 2 * kD) acc += sc[j] * (float)vptr[0];
  o[((size_t)(b * kM + m)) * kD + h * kDH + lane] = (bf16)(acc * inv);
}

// ============================================================
// driver
// ============================================================
extern "C" void kernel_launch(void* const* d_in, const int* in_sizes, int n_in,
                              void* d_out, int out_size, void* d_ws, size_t ws_size,
                              hipStream_t stream) {
  const float* patches  = (const float*)d_in[0];
  const float* pe_ln1_g = (const float*)d_in[1];
  const float* pe_ln1_b = (const float*)d_in[2];
  const float* W_pe     = (const float*)d_in[3];
  const float* b_pe     = (const float*)d_in[4];
  const float* pe_ln2_g = (const float*)d_in[5];
  const float* pe_ln2_b = (const float*)d_in[6];
  const float* pos_h    = (const float*)d_in[7];
  const float* pos_w    = (const float*)d_in[8];
  const float* ln1_g    = (const float*)d_in[9];
  const float* ln1_b    = (const float*)d_in[10];
  const float* qn_g     = (const float*)d_in[11];
  const float* qn_b     = (const float*)d_in[12];
  const float* kn_g     = (const float*)d_in[13];
  const float* kn_b     = (const float*)d_in[14];
  const float* Wq       = (const float*)d_in[15];
  const float* Wkv      = (const float*)d_in[16];
  const float* Wo       = (const float*)d_in[17];
  const float* ln2_g    = (const float*)d_in[18];
  const float* ln2_b    = (const float*)d_in[19];
  const float* W1       = (const float*)d_in[20];
  const float* b1       = (const float*)d_in[21];
  const float* W2       = (const float*)d_in[22];
  const float* b2       = (const float*)d_in[23];
  const float* fin_g    = (const float*)d_in[24];
  const float* fin_b    = (const float*)d_in[25];
  const float* pool_q   = (const float*)d_in[26];
  const float* pl_ln_g  = (const float*)d_in[27];
  const float* pl_ln_b  = (const float*)d_in[28];
  const float* pl_qn_g  = (const float*)d_in[29];
  const float* pl_qn_b  = (const float*)d_in[30];
  const float* pl_kn_g  = (const float*)d_in[31];
  const float* pl_kn_b  = (const float*)d_in[32];
  const float* pl_Wq    = (const float*)d_in[33];
  const float* pl_Wkv   = (const float*)d_in[34];
  const float* pl_Wo    = (const float*)d_in[35];
  const float* head_g   = (const float*)d_in[36];
  const float* head_b   = (const float*)d_in[37];
  const float* W_head   = (const float*)d_in[38];
  const float* b_head   = (const float*)d_in[39];
  const int* h_idx      = (const int*)d_in[40];
  const int* w_idx      = (const int*)d_in[41];
  const int* image_ids  = (const int*)d_in[42];
  float* out = (float*)d_out;

  // ---- workspace layout ----
  const size_t SZ = (size_t)kB * kN * kD;        // 2,621,440
  char* p = (char*)d_ws;
  bf16*  x    = (bf16*)p;            p += SZ * 2;                 // 5.2 MB (bf16 residual)
  bf16*  xnb  = (bf16*)p;            p += SZ * 2;                 // 5.2 MB
  char*  scratch = p;                p += 32u * 1024 * 1024;      // 32 MB
  char*  smalls = p;                 p += 1u * 1024 * 1024;       // 1 MB
  bf16*  wtbuf = (bf16*)p;                                        // 112 MB
  // scratch overlays
  bf16*  qkvbb = (bf16*)scratch;                         // [BN][3072] bf16
  bf16*  attno = (bf16*)(scratch + 16u * 1024 * 1024);   // [BN][1024] bf16
  bf16*  plnb  = (bf16*)scratch;                         // [BN][3072] bf16 (embed)
  float* emb   = (float*)(scratch + 16u * 1024 * 1024);  // [BN][1024] f32 (embed)
  bf16*  h1b   = (bf16*)scratch;                         // [BN][2048] bf16 (mlp)
  bf16*  kvpoolb = (bf16*)scratch;                       // [BN][2048] bf16 (pool)
  float* qpool   = (float*)smalls;
  bf16*  opoolb  = (bf16*)(smalls + 8192);
  float* pooled  = (float*)(smalls + 8192 + 163840);
  bf16*  pooledn = (bf16*)(smalls + 8192 + 163840 + 327680);
  int2*  spans   = (int2*)(smalls + 8192 + 163840 + 327680 + 163840);

  const int BN = kB * kN;          // 2560 rows
  const int nbyM = BN / 64;        // 40 row-blocks

  // ---- spans + all weight transposes ----
  span_kernel<<<dim3(kM + 1, kB), 64, 0, stream>>>(image_ids, spans);
  wt_all_kernel<<<dim3(768, 35), 256, 0, stream>>>(
      W_pe, Wq, Wkv, Wo, W1, W2, pl_Wq, pl_Wkv, pl_Wo, W_head, wtbuf);

  // ---- patch embedding ----
  ln_kernel<bf16><<<BN, 256, 0, stream>>>(patches, plnb, pe_ln1_g, pe_ln1_b, kPD);
  gemm64_kernel<2, false, false, false><<<(kD / 64) * nbyM, 256, 0, stream>>>(
      plnb, wtbuf + kOffPe, emb, nullptr, b_pe, nullptr, nullptr, nullptr, kPD, kD, kD / 64);
  ln_pos_kernel<<<BN, 256, 0, stream>>>(emb, x, pe_ln2_g, pe_ln2_b, pos_h, pos_w, h_idx, w_idx);

  // ---- transformer layers ----
  for (int l = 0; l < kDepth; ++l) {
    const bf16* lw = wtbuf + kLayer0 + (size_t)l * kLayerSz;
    ln_bf_kernel<<<BN, 256, 0, stream>>>(x, xnb, ln1_g + (size_t)l * kD, ln1_b + (size_t)l * kD);
    gemm64_kernel<4, true, false, false><<<(3 * kD / 128) * nbyM, 256, 0, stream>>>(
        xnb, lw, nullptr, qkvbb, nullptr, nullptr, nullptr, nullptr, kD, 3 * kD, 3 * kD / 128);
    attn_kernel<<<dim3(kH, kM + 1, kB), 256, 0, stream>>>(
        qkvbb, spans,
        qn_g + (size_t)l * kDH, qn_b + (size_t)l * kDH,
        kn_g + (size_t)l * kDH, kn_b + (size_t)l * kDH, attno);
    gemm64_kernel<2, true, false, false><<<(kD / 64) * nbyM, 256, 0, stream>>>(
        attno, lw + 3 * kMEG, nullptr, x, nullptr, x, nullptr, nullptr, kD, kD, kD / 64);
    ln_bf_kernel<<<BN, 256, 0, stream>>>(x, xnb, ln2_g + (size_t)l * kD, ln2_b + (size_t)l * kD);
    gemm64_kernel<4, true, true, false><<<(kMLP / 128) * nbyM, 256, 0, stream>>>(
        xnb, lw + 4 * kMEG, nullptr, h1b, b1 + (size_t)l * kMLP, nullptr, nullptr, nullptr, kD, kMLP, kMLP / 128);
    gemm64_kernel<2, true, false, false><<<(kD / 64) * nbyM, 256, 0, stream>>>(
        h1b, lw + 6 * kMEG, nullptr, x, b2 + (size_t)l * kD, x, nullptr, nullptr, kMLP, kD, kD / 64);
  }

  // ---- final LN (context for pooling) ----
  ln_bf_kernel<<<BN, 256, 0, stream>>>(x, xnb, fin_g, fin_b);

  // ---- attention pooling ----
  poolq_kernel<<<kH, 256, 0, stream>>>(
      pool_q, pl_ln_g, pl_ln_b, wtbuf + kOffPlWq, pl_qn_g, pl_qn_b, qpool);
  gemm64_kernel<4, true, false, true><<<(2 * kD / 128) * nbyM, 256, 0, stream>>>(
      xnb, wtbuf + kOffPlWkv, nullptr, kvpoolb, nullptr, nullptr, pl_kn_g, pl_kn_b, kD, 2 * kD, 2 * kD / 128);
  poolattn_kernel<<<kB * kM * kH, 64, 0, stream>>>(qpool, kvpoolb, spans, opoolb);
  gemm_tail_kernel<false><<<dim3(8, 2), 256, 0, stream>>>(
      opoolb, wtbuf + kOffPlWo, pooled, nullptr, nullptr, pool_q, kB * kM, kD, kD, kD, 2);

  // ---- classifier head ----
  ln_kernel<bf16><<<kB * kM, 256, 0, stream>>>(pooled, pooledn, head_g, head_b, kD);
  gemm_tail_kernel<false><<<dim3(8, 2), 256, 0, stream>>>(
      pooledn, wtbuf + kOffHead, out, nullptr, b_head, nullptr, kB * kM, kD, kNC, kNC, 0);
}

// Round 15
// 941.063 us; speedup vs baseline: 1.0087x; 1.0087x over previous
//
#include <hip/hip_runtime.h>
#include <cmath>

// ---- model constants ----
constexpr int kB = 4, kN = 640, kD = 1024, kH = 16, kDH = 64;
constexpr int kDepth = 6, kMLP = 2048, kPD = 3072, kNC = 1000, kM = 18;
constexpr float kScale = 0.125f;        // DH^-0.5
constexpr float kNegInf = -3.4028235e38f;

typedef __bf16 bf16;
typedef __attribute__((ext_vector_type(8))) __bf16 bf16x8;
typedef __attribute__((ext_vector_type(4))) __bf16 bf16x4;
typedef __attribute__((ext_vector_type(4))) float f32x4;

#define AS1 __attribute__((address_space(1)))
#define AS3 __attribute__((address_space(3)))

__device__ __forceinline__ void gload16(const void* g, void* l) {
  __builtin_amdgcn_global_load_lds((AS1 void*)g, (AS3 void*)l, 16, 0, 0);
}

// ---- wtbuf element offsets (bf16 elems) ----
constexpr size_t kMEG = 1048576;
constexpr size_t kOffPe = 0;                              // 3072x1024
constexpr size_t kLayer0 = 3 * kMEG;
constexpr size_t kLayerSz = 8 * kMEG;                     // WqT 1M | WkvT 2M | WoT 1M | W1T 2M | W2T 2M
constexpr size_t kOffPool = kLayer0 + 6 * kLayerSz;
constexpr size_t kOffPlWq = kOffPool;
constexpr size_t kOffPlWkv = kOffPool + 1 * kMEG;
constexpr size_t kOffPlWo = kOffPool + 3 * kMEG;
constexpr size_t kOffHead = kOffPool + 4 * kMEG;

// ============================================================
// Batched weight transpose (best measured variant).
// 64x64 tiles: float4 reads, LDS [64][65], bf16x8 coalesced writes.
// grid = (768, 35).
// ============================================================
__global__ __launch_bounds__(256) void wt_all_kernel(
    const float* __restrict__ pe, const float* __restrict__ wq,
    const float* __restrict__ wkv, const float* __restrict__ wo,
    const float* __restrict__ w1, const float* __restrict__ w2,
    const float* __restrict__ plq, const float* __restrict__ plkv,
    const float* __restrict__ plo, const float* __restrict__ whead,
    bf16* __restrict__ WTB) {
  const int j = blockIdx.y;
  const float* W;
  size_t doff;
  int K, Nc, Np;
  if (j == 0) {
    W = pe; K = 3072; Nc = 1024; Np = 1024; doff = kOffPe;
  } else if (j < 31) {
    const int l = (j - 1) / 5, w = (j - 1) % 5;
    const size_t lbase = kLayer0 + (size_t)l * kLayerSz;
    switch (w) {
      case 0:  W = wq  + (size_t)l * kMEG;     K = 1024; Nc = 1024; doff = lbase;            break;
      case 1:  W = wkv + (size_t)l * 2 * kMEG; K = 1024; Nc = 2048; doff = lbase + kMEG;     break;
      case 2:  W = wo  + (size_t)l * kMEG;     K = 1024; Nc = 1024; doff = lbase + 3 * kMEG; break;
      case 3:  W = w1  + (size_t)l * 2 * kMEG; K = 1024; Nc = 2048; doff = lbase + 4 * kMEG; break;
      default: W = w2  + (size_t)l * 2 * kMEG; K = 2048; Nc = 1024; doff = lbase + 6 * kMEG; break;
    }
    Np = Nc;
  } else if (j == 31) { W = plq;  K = 1024; Nc = 1024; Np = 1024; doff = kOffPlWq; }
  else if (j == 32)   { W = plkv; K = 1024; Nc = 2048; Np = 2048; doff = kOffPlWkv; }
  else if (j == 33)   { W = plo;  K = 1024; Nc = 1024; Np = 1024; doff = kOffPlWo; }
  else                { W = whead; K = 1024; Nc = 1000; Np = 1024; doff = kOffHead; }
  const int nbx = Np >> 6;
  const int ntiles = nbx * (K >> 6);
  const int tile = blockIdx.x;
  if (tile >= ntiles) return;
  const int n0 = (tile % nbx) * 64, k0 = (tile / nbx) * 64;
  bf16* WT = WTB + doff;
  __shared__ float s[64][65];
  const int tid = threadIdx.x;
  if (n0 + 64 <= Nc) {
#pragma unroll
    for (int i = 0; i < 4; ++i) {
      const int c = i * 256 + tid;
      const int r = c >> 4, cq = c & 15;
      const float4 v = *(const float4*)(W + (size_t)(k0 + r) * Nc + n0 + cq * 4);
      s[r][cq * 4 + 0] = v.x; s[r][cq * 4 + 1] = v.y;
      s[r][cq * 4 + 2] = v.z; s[r][cq * 4 + 3] = v.w;
    }
  } else {
#pragma unroll
    for (int i = 0; i < 4; ++i) {
      const int c = i * 256 + tid;
      const int r = c >> 4, cq = c & 15;
#pragma unroll
      for (int e = 0; e < 4; ++e) {
        const int n = n0 + cq * 4 + e;
        s[r][cq * 4 + e] = (n < Nc) ? W[(size_t)(k0 + r) * Nc + n] : 0.f;
      }
    }
  }
  __syncthreads();
#pragma unroll
  for (int i = 0; i < 2; ++i) {
    const int c = i * 256 + tid;
    const int n = c >> 3, kq = c & 7;
    bf16x8 w;
#pragma unroll
    for (int e = 0; e < 8; ++e) w[e] = (bf16)s[kq * 8 + e][n];
    *(bf16x8*)(WT + (size_t)(n0 + n) * K + k0 + kq * 8) = w;
  }
}

// ============================================================
// Image-span precompute.
// ============================================================
__global__ __launch_bounds__(64) void span_kernel(
    const int* __restrict__ ids, int2* __restrict__ spans) {
  const int img = blockIdx.x, b = blockIdx.y;
  const int want = (img < kM) ? img : -1;
  int lo = kN, hi = -1;
  for (int j = threadIdx.x; j < kN; j += 64) {
    if (ids[b * kN + j] == want) { lo = min(lo, j); hi = max(hi, j); }
  }
#pragma unroll
  for (int off = 32; off; off >>= 1) {
    lo = min(lo, __shfl_xor(lo, off));
    hi = max(hi, __shfl_xor(hi, off));
  }
  if (threadIdx.x == 0) spans[b * (kM + 1) + img] = make_int2(lo, hi);
}

// ============================================================
// LayerNorm, f32 input. float4 loads.
// ============================================================
template <typename OT>
__global__ __launch_bounds__(256) void ln_kernel(
    const float* __restrict__ in, OT* __restrict__ out,
    const float* __restrict__ g, const float* __restrict__ b, int K) {
  const int row = blockIdx.x;
  const float* x = in + (size_t)row * K;
  OT* o = out + (size_t)row * K;
  const int K4 = K >> 2;
  float s = 0.f, s2 = 0.f;
  for (int c = threadIdx.x; c < K4; c += 256) {
    const float4 v = ((const float4*)x)[c];
    s += v.x + v.y + v.z + v.w;
    s2 += v.x * v.x + v.y * v.y + v.z * v.z + v.w * v.w;
  }
#pragma unroll
  for (int off = 32; off; off >>= 1) { s += __shfl_down(s, off); s2 += __shfl_down(s2, off); }
  __shared__ float ls[4], ls2[4];
  __shared__ float sm, sr;
  const int wid = threadIdx.x >> 6, lane = threadIdx.x & 63;
  if (lane == 0) { ls[wid] = s; ls2[wid] = s2; }
  __syncthreads();
  if (threadIdx.x == 0) {
    float a = ls[0] + ls[1] + ls[2] + ls[3];
    float a2 = ls2[0] + ls2[1] + ls2[2] + ls2[3];
    float mean = a / K;
    float var = a2 / K - mean * mean;
    sm = mean; sr = rsqrtf(var + 1e-5f);
  }
  __syncthreads();
  const float mean = sm, r = sr;
  for (int c = threadIdx.x; c < K4; c += 256) {
    const float4 v = ((const float4*)x)[c];
    const float4 gv = ((const float4*)g)[c];
    const float4 bv = ((const float4*)b)[c];
    const int d = c * 4;
    o[d + 0] = (OT)((v.x - mean) * r * gv.x + bv.x);
    o[d + 1] = (OT)((v.y - mean) * r * gv.y + bv.y);
    o[d + 2] = (OT)((v.z - mean) * r * gv.z + bv.z);
    o[d + 3] = (OT)((v.w - mean) * r * gv.w + bv.w);
  }
}

// ============================================================
// LayerNorm, bf16 in -> bf16 out, K=1024 fixed.
// ============================================================
__global__ __launch_bounds__(256) void ln_bf_kernel(
    const bf16* __restrict__ in, bf16* __restrict__ out,
    const float* __restrict__ g, const float* __restrict__ b) {
  const int row = blockIdx.x;
  const bf16* x = in + (size_t)row * kD;
  bf16* o = out + (size_t)row * kD;
  const int c = threadIdx.x;
  const bf16x4 v4 = ((const bf16x4*)x)[c];
  float f[4];
  float s = 0.f, s2 = 0.f;
#pragma unroll
  for (int e = 0; e < 4; ++e) {
    f[e] = (float)v4[e];
    s += f[e]; s2 += f[e] * f[e];
  }
#pragma unroll
  for (int off = 32; off; off >>= 1) { s += __shfl_down(s, off); s2 += __shfl_down(s2, off); }
  __shared__ float ls[4], ls2[4];
  __shared__ float sm, sr;
  const int wid = c >> 6, lane = c & 63;
  if (lane == 0) { ls[wid] = s; ls2[wid] = s2; }
  __syncthreads();
  if (c == 0) {
    float a = ls[0] + ls[1] + ls[2] + ls[3];
    float a2 = ls2[0] + ls2[1] + ls2[2] + ls2[3];
    float mean = a / kD;
    sm = mean; sr = rsqrtf(a2 / kD - mean * mean + 1e-5f);
  }
  __syncthreads();
  const float mean = sm, r = sr;
  const float4 gv = ((const float4*)g)[c];
  const float4 bv = ((const float4*)b)[c];
  bf16x4 ov;
  ov[0] = (bf16)((f[0] - mean) * r * gv.x + bv.x);
  ov[1] = (bf16)((f[1] - mean) * r * gv.y + bv.y);
  ov[2] = (bf16)((f[2] - mean) * r * gv.z + bv.z);
  ov[3] = (bf16)((f[3] - mean) * r * gv.w + bv.w);
  ((bf16x4*)o)[c] = ov;
}

// ============================================================
// Fused pe_ln2 + factorized pos-embed add. f32 in, bf16 out.
// ============================================================
__global__ __launch_bounds__(256) void ln_pos_kernel(
    const float* __restrict__ in, bf16* __restrict__ out,
    const float* __restrict__ g, const float* __restrict__ b,
    const float* __restrict__ ph, const float* __restrict__ pw,
    const int* __restrict__ hi, const int* __restrict__ wi) {
  const int row = blockIdx.x;
  const float* x = in + (size_t)row * kD;
  bf16* o = out + (size_t)row * kD;
  const int c = threadIdx.x;
  const float4 v = ((const float4*)x)[c];
  float s = v.x + v.y + v.z + v.w;
  float s2 = v.x * v.x + v.y * v.y + v.z * v.z + v.w * v.w;
#pragma unroll
  for (int off = 32; off; off >>= 1) { s += __shfl_down(s, off); s2 += __shfl_down(s2, off); }
  __shared__ float ls[4], ls2[4];
  __shared__ float sm, sr;
  const int wid = threadIdx.x >> 6, lane = threadIdx.x & 63;
  if (lane == 0) { ls[wid] = s; ls2[wid] = s2; }
  __syncthreads();
  if (threadIdx.x == 0) {
    float a = ls[0] + ls[1] + ls[2] + ls[3];
    float a2 = ls2[0] + ls2[1] + ls2[2] + ls2[3];
    float mean = a / kD;
    float var = a2 / kD - mean * mean;
    sm = mean; sr = rsqrtf(var + 1e-5f);
  }
  __syncthreads();
  const float mean = sm, r = sr;
  const float4* phr = (const float4*)(ph + (size_t)hi[row] * kD);
  const float4* pwr = (const float4*)(pw + (size_t)wi[row] * kD);
  const float4 gv = ((const float4*)g)[c];
  const float4 bv = ((const float4*)b)[c];
  const float4 hv = phr[c], wv = pwr[c];
  bf16x4 ov;
  ov[0] = (bf16)((v.x - mean) * r * gv.x + bv.x + hv.x + wv.x);
  ov[1] = (bf16)((v.y - mean) * r * gv.y + bv.y + hv.y + wv.y);
  ov[2] = (bf16)((v.z - mean) * r * gv.z + bv.z + hv.z + wv.z);
  ov[3] = (bf16)((v.w - mean) * r * gv.w + bv.w + hv.w + wv.w);
  ((bf16x4*)o)[c] = ov;
}

// ============================================================
// Fused pool-query chain: LN(pool_q) -> @pl_Wq^T(bf16) -> head LN.
// ============================================================
__global__ __launch_bounds__(256) void poolq_kernel(
    const float* __restrict__ pq, const float* __restrict__ lg,
    const float* __restrict__ lb, const bf16* __restrict__ WqT,
    const float* __restrict__ qg, const float* __restrict__ qb,
    float* __restrict__ qpool) {
  const int h = blockIdx.x, tid = threadIdx.x;
  __shared__ float qs[1024];
  __shared__ float red[256];
  __shared__ float ls[4], ls2[4];
  __shared__ float sm, sr;
  const float4 v = ((const float4*)pq)[tid];
  float s = v.x + v.y + v.z + v.w;
  float s2 = v.x * v.x + v.y * v.y + v.z * v.z + v.w * v.w;
#pragma unroll
  for (int off = 32; off; off >>= 1) { s += __shfl_down(s, off); s2 += __shfl_down(s2, off); }
  const int wid = tid >> 6, lane = tid & 63;
  if (lane == 0) { ls[wid] = s; ls2[wid] = s2; }
  __syncthreads();
  if (tid == 0) {
    float a = ls[0] + ls[1] + ls[2] + ls[3];
    float a2 = ls2[0] + ls2[1] + ls2[2] + ls2[3];
    float mean = a / kD;
    sm = mean; sr = rsqrtf(a2 / kD - mean * mean + 1e-5f);
  }
  __syncthreads();
  {
    const float mean = sm, r = sr;
    const float4 gv = ((const float4*)lg)[tid];
    const float4 bv = ((const float4*)lb)[tid];
    qs[tid * 4 + 0] = (v.x - mean) * r * gv.x + bv.x;
    qs[tid * 4 + 1] = (v.y - mean) * r * gv.y + bv.y;
    qs[tid * 4 + 2] = (v.z - mean) * r * gv.z + bv.z;
    qs[tid * 4 + 3] = (v.w - mean) * r * gv.w + bv.w;
  }
  __syncthreads();
  const int d = tid & 63, qq = tid >> 6;
  const bf16* wrow = WqT + (size_t)(h * 64 + d) * 1024 + qq * 256;
  const float* qp = qs + qq * 256;
  float part = 0.f;
  for (int k = 0; k < 256; k += 8) {
    const bf16x8 w8 = *(const bf16x8*)(wrow + k);
#pragma unroll
    for (int e = 0; e < 8; ++e) part += qp[k + e] * (float)w8[e];
  }
  red[tid] = part;
  __syncthreads();
  if (tid < 64) {
    const float dot = red[tid] + red[tid + 64] + red[tid + 128] + red[tid + 192];
    float hs = dot, hs2 = dot * dot;
#pragma unroll
    for (int off = 32; off; off >>= 1) { hs += __shfl_xor(hs, off); hs2 += __shfl_xor(hs2, off); }
    const float m = hs * (1.f / kDH);
    const float r = rsqrtf(hs2 * (1.f / kDH) - m * m + 1e-5f);
    qpool[h * 64 + tid] = (dot - m) * r * qg[tid] + qb[tid];
  }
}

// ============================================================
// 64x(NI*32) MFMA GEMM, BK=64, 2-buffer LDS + global_load_lds
// prefetch (best measured form). T2 XOR-swizzle, XCD-chunked
// blockIdx swizzle. res bf16. HLN for pool kv (NI=4).
// ============================================================
template <int NI, bool OUT_BF, bool GELU, bool HLN>
__global__ __launch_bounds__(256) void gemm64_kernel(
    const bf16* __restrict__ A, const bf16* __restrict__ WT,
    float* __restrict__ Cf, bf16* __restrict__ Cb,
    const float* __restrict__ bias, const bf16* __restrict__ res,
    const float* __restrict__ hg, const float* __restrict__ hb,
    int K, int Ncol, int nbx) {
  constexpr int BN = NI * 32;
  __shared__ __align__(16) bf16 As[2][64 * 64];
  __shared__ __align__(16) bf16 Bs[2][BN * 64];
  const int tid = threadIdx.x, lane = tid & 63, wid = tid >> 6;
  const int wr = wid >> 1, wc = wid & 1;
  const int cpx = gridDim.x >> 3;
  const int swz = (blockIdx.x & 7) * cpx + (blockIdx.x >> 3);
  const int row0 = (swz / nbx) * 64, col0 = (swz % nbx) * BN;
  const int fr = lane & 15, fg = lane >> 4;
  f32x4 acc[2][NI] = {};
  bf16* sA = As[0]; bf16* sB = Bs[0];
  bf16* dA = As[1]; bf16* dB = Bs[1];

  auto stage = [&](bf16* tA, bf16* tB, int kt) {
#pragma unroll
    for (int i = 0; i < 2; ++i) {
      const int c = i * 256 + tid;
      const int r = c >> 3, ci = c & 7;
      gload16(A + (size_t)(row0 + r) * K + kt + ((ci ^ (r & 7)) * 8),
              tA + (i * 256 + wid * 64) * 8);
    }
#pragma unroll
    for (int i = 0; i < NI; ++i) {
      const int c = i * 256 + tid;
      const int r = c >> 3, ci = c & 7;
      gload16(WT + (size_t)(col0 + r) * K + kt + ((ci ^ (r & 7)) * 8),
              tB + (i * 256 + wid * 64) * 8);
    }
  };
  auto compute = [&](const bf16* tA, const bf16* tB) {
#pragma unroll
    for (int kk = 0; kk < 2; ++kk) {
      bf16x8 af[2], bfr[NI];
#pragma unroll
      for (int mi = 0; mi < 2; ++mi) {
        const int r = wr * 32 + mi * 16 + fr;
        af[mi] = *(const bf16x8*)(tA + r * 64 + (((kk * 4 + fg) ^ (r & 7)) * 8));
      }
#pragma unroll
      for (int ni = 0; ni < NI; ++ni) {
        const int r = wc * (NI * 16) + ni * 16 + fr;
        bfr[ni] = *(const bf16x8*)(tB + r * 64 + (((kk * 4 + fg) ^ (r & 7)) * 8));
      }
#pragma unroll
      for (int mi = 0; mi < 2; ++mi)
#pragma unroll
        for (int ni = 0; ni < NI; ++ni)
          acc[mi][ni] = __builtin_amdgcn_mfma_f32_16x16x32_bf16(af[mi], bfr[ni], acc[mi][ni], 0, 0, 0);
    }
  };

  const int NT = K >> 6;
  stage(sA, sB, 0);
  __syncthreads();
  for (int t = 1; t < NT; ++t) {
    stage(dA, dB, t * 64);
    compute(sA, sB);
    __syncthreads();
    bf16* u;
    u = sA; sA = dA; dA = u;
    u = sB; sB = dB; dB = u;
  }
  compute(sA, sB);

  const int rb = row0 + wr * 32 + fg * 4;
  const int cb = col0 + wc * (NI * 16) + fr;
  float hm[2][4], hr[2][4];
  if (HLN) {
#pragma unroll
    for (int mi = 0; mi < 2; ++mi)
#pragma unroll
      for (int r = 0; r < 4; ++r) {
        float s = 0.f, s2 = 0.f;
#pragma unroll
        for (int ni = 0; ni < NI; ++ni) {
          const float v = acc[mi][ni][r];
          s += v; s2 += v * v;
        }
#pragma unroll
        for (int off = 1; off < 16; off <<= 1) {
          s += __shfl_xor(s, off); s2 += __shfl_xor(s2, off);
        }
        const float m = s * (1.f / kDH);
        hm[mi][r] = m;
        hr[mi][r] = rsqrtf(s2 * (1.f / kDH) - m * m + 1e-5f);
      }
  }
  const bool kHalf = HLN && (cb < kD);
#pragma unroll
  for (int mi = 0; mi < 2; ++mi) {
#pragma unroll
    for (int ni = 0; ni < NI; ++ni) {
      const int cc = cb + ni * 16;
      const float bb = bias ? bias[cc] : 0.f;
      const float hgv = HLN ? hg[ni * 16 + fr] : 0.f;
      const float hbv = HLN ? hb[ni * 16 + fr] : 0.f;
#pragma unroll
      for (int r = 0; r < 4; ++r) {
        const int rr = rb + mi * 16 + r;
        float v = acc[mi][ni][r] + bb;
        if (res) v += (float)res[(size_t)rr * Ncol + cc];
        if (GELU) v = 0.5f * v * (1.f + erff(v * 0.70710678118654752f));
        if (HLN && kHalf) v = (v - hm[mi][r]) * hr[mi][r] * hgv + hbv;
        if (OUT_BF) Cb[(size_t)rr * Ncol + cc] = (bf16)v;
        else        Cf[(size_t)rr * Ncol + cc] = v;
      }
    }
  }
}

// ============================================================
// Guarded tail GEMM (reg-staged 64x128): small M.
// ============================================================
template <bool OUT_BF>
__global__ __launch_bounds__(256) void gemm_tail_kernel(
    const bf16* __restrict__ A, const bf16* __restrict__ WT,
    float* __restrict__ Cf, bf16* __restrict__ Cb,
    const float* __restrict__ bias, const float* __restrict__ resv,
    int Mr, int K, int Nc, int ldc, int resmode) {
  __shared__ __align__(16) bf16 As[64][40];
  __shared__ __align__(16) bf16 Bs[128][40];
  const int tid = threadIdx.x;
  const int lane = tid & 63, wid = tid >> 6;
  const int row0 = blockIdx.y * 64, col0 = blockIdx.x * 128;
  f32x4 acc[4][2] = {};
  const int am = tid >> 2, ako = (tid & 3) * 8;
  const int fr = lane & 15, fg = (lane >> 4) * 8;
  for (int k0 = 0; k0 < K; k0 += 32) {
    if (row0 + am < Mr)
      *(bf16x8*)&As[am][ako] = *(const bf16x8*)(A + (size_t)(row0 + am) * K + k0 + ako);
    else {
      bf16x8 z = {};
      *(bf16x8*)&As[am][ako] = z;
    }
#pragma unroll
    for (int it = 0; it < 2; ++it) {
      const int c = it * 256 + tid;
      const int n = c >> 2, ko = (c & 3) * 8;
      *(bf16x8*)&Bs[n][ko] = *(const bf16x8*)(WT + (size_t)(col0 + n) * K + k0 + ko);
    }
    __syncthreads();
    bf16x8 af[4], bfr[2];
#pragma unroll
    for (int mi = 0; mi < 4; ++mi) af[mi] = *(const bf16x8*)&As[mi * 16 + fr][fg];
#pragma unroll
    for (int ni = 0; ni < 2; ++ni) bfr[ni] = *(const bf16x8*)&Bs[wid * 32 + ni * 16 + fr][fg];
#pragma unroll
    for (int mi = 0; mi < 4; ++mi)
#pragma unroll
      for (int ni = 0; ni < 2; ++ni)
        acc[mi][ni] = __builtin_amdgcn_mfma_f32_16x16x32_bf16(af[mi], bfr[ni], acc[mi][ni], 0, 0, 0);
    __syncthreads();
  }
  const int r4 = (lane >> 4) * 4;
  const int cc0 = col0 + wid * 32 + (lane & 15);
#pragma unroll
  for (int mi = 0; mi < 4; ++mi) {
#pragma unroll
    for (int ni = 0; ni < 2; ++ni) {
      const int cc = cc0 + ni * 16;
      if (cc >= Nc) continue;
#pragma unroll
      for (int r = 0; r < 4; ++r) {
        const int rr = row0 + mi * 16 + r4 + r;
        if (rr >= Mr) continue;
        float v = acc[mi][ni][r];
        if (bias) v += bias[cc];
        if (resmode == 1) v += resv[(size_t)rr * ldc + cc];
        else if (resmode == 2) v += resv[cc];
        if (OUT_BF) Cb[(size_t)rr * ldc + cc] = (bf16)v;
        else        Cf[(size_t)rr * ldc + cc] = v;
      }
    }
  }
}

// ============================================================
// Block-diagonal MFMA attention, bf16 qkv input [B,N,3072].
// Spans precomputed.
// ============================================================
__global__ __launch_bounds__(256) void attn_kernel(
    const bf16* __restrict__ qkv, const int2* __restrict__ spans,
    const float* __restrict__ qg, const float* __restrict__ qb,
    const float* __restrict__ kg, const float* __restrict__ kb,
    bf16* __restrict__ o) {
  const int h = blockIdx.x, img = blockIdx.y, b = blockIdx.z;
  const int tid = threadIdx.x, lane = tid & 63, wid = tid >> 6;
  __shared__ __align__(16) bf16 Qs[64][72];
  __shared__ __align__(16) bf16 Ks[64][72];
  __shared__ __align__(16) bf16 Vt[64][72];
  __shared__ __align__(16) bf16 Ps[64][72];
  const int2 sp = spans[b * (kM + 1) + img];
  if (sp.y < 0) return;
  const int start = sp.x, T = sp.y - sp.x + 1;
  if (img == kM) {
    for (int j = start + wid; j <= sp.y; j += 4)
      o[((size_t)(b * kN + j)) * kD + h * kDH + lane] = (bf16)0.f;
    return;
  }
#pragma unroll
  for (int it = 0; it < 2; ++it) {
    const int ch = it * 256 + tid;
    const int r = ch >> 3, d0 = (ch & 7) * 8;
    if (r < T) {
      const bf16* base = qkv + ((size_t)(b * kN + start + r)) * 3072 + h * kDH + d0;
      const bf16x8 qv = *(const bf16x8*)(base);
      const bf16x8 kv = *(const bf16x8*)(base + 1024);
      const bf16x8 vv = *(const bf16x8*)(base + 2048);
      float qf[8], kf[8];
      float sq = 0.f, sq2 = 0.f, sk = 0.f, sk2 = 0.f;
#pragma unroll
      for (int e = 0; e < 8; ++e) {
        qf[e] = (float)qv[e]; kf[e] = (float)kv[e];
        sq += qf[e]; sq2 += qf[e] * qf[e];
        sk += kf[e]; sk2 += kf[e] * kf[e];
      }
#pragma unroll
      for (int off = 1; off < 8; off <<= 1) {
        sq += __shfl_xor(sq, off); sq2 += __shfl_xor(sq2, off);
        sk += __shfl_xor(sk, off); sk2 += __shfl_xor(sk2, off);
      }
      const float qm = sq * (1.f / 64);
      const float qr = rsqrtf(sq2 * (1.f / 64) - qm * qm + 1e-5f);
      const float km = sk * (1.f / 64);
      const float kr = rsqrtf(sk2 * (1.f / 64) - km * km + 1e-5f);
      bf16x8 qw, kw;
#pragma unroll
      for (int e = 0; e < 8; ++e) {
        qw[e] = (bf16)((qf[e] - qm) * qr * qg[d0 + e] + qb[d0 + e]);
        kw[e] = (bf16)((kf[e] - km) * kr * kg[d0 + e] + kb[d0 + e]);
      }
      *(bf16x8*)&Qs[r][d0] = qw;
      *(bf16x8*)&Ks[r][d0] = kw;
#pragma unroll
      for (int e = 0; e < 8; ++e) Vt[d0 + e][r] = vv[e];
    } else {
      const bf16x8 z = {};
      *(bf16x8*)&Qs[r][d0] = z;
      *(bf16x8*)&Ks[r][d0] = z;
#pragma unroll
      for (int e = 0; e < 8; ++e) Vt[d0 + e][r] = (bf16)0.f;
    }
  }
  __syncthreads();
  const int fr = lane & 15, fg = lane >> 4;
  const int r0 = wid * 16;
  f32x4 sacc[4] = {};
#pragma unroll
  for (int k0 = 0; k0 < 64; k0 += 32) {
    const bf16x8 aq = *(const bf16x8*)&Qs[r0 + fr][k0 + fg * 8];
#pragma unroll
    for (int ni = 0; ni < 4; ++ni) {
      const bf16x8 bk = *(const bf16x8*)&Ks[ni * 16 + fr][k0 + fg * 8];
      sacc[ni] = __builtin_amdgcn_mfma_f32_16x16x32_bf16(aq, bk, sacc[ni], 0, 0, 0);
    }
  }
  float inv[4];
#pragma unroll
  for (int r = 0; r < 4; ++r) {
    float mx = kNegInf;
#pragma unroll
    for (int ni = 0; ni < 4; ++ni) {
      const float s = (ni * 16 + fr < T) ? sacc[ni][r] * kScale : kNegInf;
      sacc[ni][r] = s;
      mx = fmaxf(mx, s);
    }
#pragma unroll
    for (int off = 1; off < 16; off <<= 1) mx = fmaxf(mx, __shfl_xor(mx, off));
    float sum = 0.f;
#pragma unroll
    for (int ni = 0; ni < 4; ++ni) {
      const float p = __expf(sacc[ni][r] - mx);
      sacc[ni][r] = p;
      sum += p;
    }
#pragma unroll
    for (int off = 1; off < 16; off <<= 1) sum += __shfl_xor(sum, off);
    inv[r] = 1.f / sum;
  }
#pragma unroll
  for (int ni = 0; ni < 4; ++ni)
#pragma unroll
    for (int r = 0; r < 4; ++r)
      Ps[r0 + fg * 4 + r][ni * 16 + fr] = (bf16)sacc[ni][r];
  f32x4 oacc[4] = {};
#pragma unroll
  for (int k0 = 0; k0 < 64; k0 += 32) {
    const bf16x8 ap = *(const bf16x8*)&Ps[r0 + fr][k0 + fg * 8];
#pragma unroll
    for (int ni = 0; ni < 4; ++ni) {
      const bf16x8 bv = *(const bf16x8*)&Vt[ni * 16 + fr][k0 + fg * 8];
      oacc[ni] = __builtin_amdgcn_mfma_f32_16x16x32_bf16(ap, bv, oacc[ni], 0, 0, 0);
    }
  }
#pragma unroll
  for (int r = 0; r < 4; ++r) {
    const int i = r0 + fg * 4 + r;
    if (i < T) {
      const size_t orow = ((size_t)(b * kN + start + i)) * kD + h * kDH;
      const float iv = inv[r];
#pragma unroll
      for (int ni = 0; ni < 4; ++ni)
        o[orow + ni * 16 + fr] = (bf16)(oacc[ni][r] * iv);
    }
  }
}

// ============================================================
// Attention pooling: one wave per (b,m,h). kv bf16 [B,N,2048].
// ============================================================
__global__ __launch_bounds__(64) void poolattn_kernel(
    const float* __restrict__ qp, const bf16* __restrict__ kv,
    const int2* __restrict__ spans, bf16* __restrict__ o) {
  const int blk = blockIdx.x;
  const int h = blk % kH;
  const int bm = blk / kH;
  const int m = bm % kM, b = bm / kM;
  const int lane = threadIdx.x;
  __shared__ float sc[kN];
  __shared__ float qs[kDH];
  qs[lane] = qp[h * kDH + lane];
  __syncthreads();
  const int2 sp = spans[b * (kM + 1) + m];
  const int jlo = sp.x, jhi = sp.y + 1;
  float mymax = kNegInf;
  for (int j = jlo + lane; j < jhi; j += 64) {
    const bf16* krow = kv + ((size_t)(b * kN + j)) * (2 * kD) + h * kDH;
    float dot = 0.f;
#pragma unroll
    for (int d = 0; d < kDH; ++d) dot += qs[d] * (float)krow[d];
    const float s = dot * kScale;
    sc[j] = s;
    mymax = fmaxf(mymax, s);
  }
#pragma unroll
  for (int off = 32; off; off >>= 1) mymax = fmaxf(mymax, __shfl_xor(mymax, off));
  float mysum = 0.f;
  for (int j = jlo + lane; j < jhi; j += 64) {
    const float p = __expf(sc[j] - mymax);
    sc[j] = p;
    mysum += p;
  }
#pragma unroll
  for (int off = 32; off; off >>= 1) mysum += __shfl_xor(mysum, off);
  const float inv = 1.f / mysum;
  __syncthreads();
  float acc = 0.f;
  const bf16* vptr = kv + ((size_t)(b * kN + jlo)) * (2 * kD) + kD + h * kDH + lane;
  for (int j = jlo; j < jhi; ++j, vptr += 2 * kD) acc += sc[j] * (float)vptr[0];
  o[((size_t)(b * kM + m)) * kD + h * kDH + lane] = (bf16)(acc * inv);
}

// ============================================================
// driver
// ============================================================
extern "C" void kernel_launch(void* const* d_in, const int* in_sizes, int n_in,
                              void* d_out, int out_size, void* d_ws, size_t ws_size,
                              hipStream_t stream) {
  const float* patches  = (const float*)d_in[0];
  const float* pe_ln1_g = (const float*)d_in[1];
  const float* pe_ln1_b = (const float*)d_in[2];
  const float* W_pe     = (const float*)d_in[3];
  const float* b_pe     = (const float*)d_in[4];
  const float* pe_ln2_g = (const float*)d_in[5];
  const float* pe_ln2_b = (const float*)d_in[6];
  const float* pos_h    = (const float*)d_in[7];
  const float* pos_w    = (const float*)d_in[8];
  const float* ln1_g    = (const float*)d_in[9];
  const float* ln1_b    = (const float*)d_in[10];
  const float* qn_g     = (const float*)d_in[11];
  const float* qn_b     = (const float*)d_in[12];
  const float* kn_g     = (const float*)d_in[13];
  const float* kn_b     = (const float*)d_in[14];
  const float* Wq       = (const float*)d_in[15];
  const float* Wkv      = (const float*)d_in[16];
  const float* Wo       = (const float*)d_in[17];
  const float* ln2_g    = (const float*)d_in[18];
  const float* ln2_b    = (const float*)d_in[19];
  const float* W1       = (const float*)d_in[20];
  const float* b1       = (const float*)d_in[21];
  const float* W2       = (const float*)d_in[22];
  const float* b2       = (const float*)d_in[23];
  const float* fin_g    = (const float*)d_in[24];
  const float* fin_b    = (const float*)d_in[25];
  const float* pool_q   = (const float*)d_in[26];
  const float* pl_ln_g  = (const float*)d_in[27];
  const float* pl_ln_b  = (const float*)d_in[28];
  const float* pl_qn_g  = (const float*)d_in[29];
  const float* pl_qn_b  = (const float*)d_in[30];
  const float* pl_kn_g  = (const float*)d_in[31];
  const float* pl_kn_b  = (const float*)d_in[32];
  const float* pl_Wq    = (const float*)d_in[33];
  const float* pl_Wkv   = (const float*)d_in[34];
  const float* pl_Wo    = (const float*)d_in[35];
  const float* head_g   = (const float*)d_in[36];
  const float* head_b   = (const float*)d_in[37];
  const float* W_head   = (const float*)d_in[38];
  const float* b_head   = (const float*)d_in[39];
  const int* h_idx      = (const int*)d_in[40];
  const int* w_idx      = (const int*)d_in[41];
  const int* image_ids  = (const int*)d_in[42];
  float* out = (float*)d_out;

  // ---- workspace layout ----
  const size_t SZ = (size_t)kB * kN * kD;        // 2,621,440
  char* p = (char*)d_ws;
  bf16*  x    = (bf16*)p;            p += SZ * 2;                 // 5.2 MB (bf16 residual)
  bf16*  xnb  = (bf16*)p;            p += SZ * 2;                 // 5.2 MB
  char*  scratch = p;                p += 32u * 1024 * 1024;      // 32 MB
  char*  smalls = p;                 p += 1u * 1024 * 1024;       // 1 MB
  bf16*  wtbuf = (bf16*)p;                                        // 112 MB
  // scratch overlays
  bf16*  qkvbb = (bf16*)scratch;                         // [BN][3072] bf16
  bf16*  attno = (bf16*)(scratch + 16u * 1024 * 1024);   // [BN][1024] bf16
  bf16*  plnb  = (bf16*)scratch;                         // [BN][3072] bf16 (embed)
  float* emb   = (float*)(scratch + 16u * 1024 * 1024);  // [BN][1024] f32 (embed)
  bf16*  h1b   = (bf16*)scratch;                         // [BN][2048] bf16 (mlp)
  bf16*  kvpoolb = (bf16*)scratch;                       // [BN][2048] bf16 (pool)
  float* qpool   = (float*)smalls;
  bf16*  opoolb  = (bf16*)(smalls + 8192);
  float* pooled  = (float*)(smalls + 8192 + 163840);
  bf16*  pooledn = (bf16*)(smalls + 8192 + 163840 + 327680);
  int2*  spans   = (int2*)(smalls + 8192 + 163840 + 327680 + 163840);

  const int BN = kB * kN;          // 2560 rows
  const int nbyM = BN / 64;        // 40 row-blocks

  // ---- spans + all weight transposes ----
  span_kernel<<<dim3(kM + 1, kB), 64, 0, stream>>>(image_ids, spans);
  wt_all_kernel<<<dim3(768, 35), 256, 0, stream>>>(
      W_pe, Wq, Wkv, Wo, W1, W2, pl_Wq, pl_Wkv, pl_Wo, W_head, wtbuf);

  // ---- patch embedding ----
  ln_kernel<bf16><<<BN, 256, 0, stream>>>(patches, plnb, pe_ln1_g, pe_ln1_b, kPD);
  gemm64_kernel<2, false, false, false><<<(kD / 64) * nbyM, 256, 0, stream>>>(
      plnb, wtbuf + kOffPe, emb, nullptr, b_pe, nullptr, nullptr, nullptr, kPD, kD, kD / 64);
  ln_pos_kernel<<<BN, 256, 0, stream>>>(emb, x, pe_ln2_g, pe_ln2_b, pos_h, pos_w, h_idx, w_idx);

  // ---- transformer layers ----
  for (int l = 0; l < kDepth; ++l) {
    const bf16* lw = wtbuf + kLayer0 + (size_t)l * kLayerSz;
    ln_bf_kernel<<<BN, 256, 0, stream>>>(x, xnb, ln1_g + (size_t)l * kD, ln1_b + (size_t)l * kD);
    gemm64_kernel<4, true, false, false><<<(3 * kD / 128) * nbyM, 256, 0, stream>>>(
        xnb, lw, nullptr, qkvbb, nullptr, nullptr, nullptr, nullptr, kD, 3 * kD, 3 * kD / 128);
    attn_kernel<<<dim3(kH, kM + 1, kB), 256, 0, stream>>>(
        qkvbb, spans,
        qn_g + (size_t)l * kDH, qn_b + (size_t)l * kDH,
        kn_g + (size_t)l * kDH, kn_b + (size_t)l * kDH, attno);
    gemm64_kernel<2, true, false, false><<<(kD / 64) * nbyM, 256, 0, stream>>>(
        attno, lw + 3 * kMEG, nullptr, x, nullptr, x, nullptr, nullptr, kD, kD, kD / 64);
    ln_bf_kernel<<<BN, 256, 0, stream>>>(x, xnb, ln2_g + (size_t)l * kD, ln2_b + (size_t)l * kD);
    gemm64_kernel<4, true, true, false><<<(kMLP / 128) * nbyM, 256, 0, stream>>>(
        xnb, lw + 4 * kMEG, nullptr, h1b, b1 + (size_t)l * kMLP, nullptr, nullptr, nullptr, kD, kMLP, kMLP / 128);
    gemm64_kernel<2, true, false, false><<<(kD / 64) * nbyM, 256, 0, stream>>>(
        h1b, lw + 6 * kMEG, nullptr, x, b2 + (size_t)l * kD, x, nullptr, nullptr, kMLP, kD, kD / 64);
  }

  // ---- final LN (context for pooling) ----
  ln_bf_kernel<<<BN, 256, 0, stream>>>(x, xnb, fin_g, fin_b);

  // ---- attention pooling ----
  poolq_kernel<<<kH, 256, 0, stream>>>(
      pool_q, pl_ln_g, pl_ln_b, wtbuf + kOffPlWq, pl_qn_g, pl_qn_b, qpool);
  gemm64_kernel<4, true, false, true><<<(2 * kD / 128) * nbyM, 256, 0, stream>>>(
      xnb, wtbuf + kOffPlWkv, nullptr, kvpoolb, nullptr, nullptr, pl_kn_g, pl_kn_b, kD, 2 * kD, 2 * kD / 128);
  poolattn_kernel<<<kB * kM * kH, 64, 0, stream>>>(qpool, kvpoolb, spans, opoolb);
  gemm_tail_kernel<false><<<dim3(8, 2), 256, 0, stream>>>(
      opoolb, wtbuf + kOffPlWo, pooled, nullptr, nullptr, pool_q, kB * kM, kD, kD, kD, 2);

  // ---- classifier head ----
  ln_kernel<bf16><<<kB * kM, 256, 0, stream>>>(pooled, pooledn, head_g, head_b, kD);
  gemm_tail_kernel<false><<<dim3(8, 2), 256, 0, stream>>>(
      pooledn, wtbuf + kOffHead, out, nullptr, b_head, nullptr, kB * kM, kD, kNC, kNC, 0);
}